// Round 9
// baseline (153.823 us; speedup 1.0000x reference)
//
#include <hip/hip_runtime.h>
#include <hip/hip_bf16.h>

#define DMODEL 768
#define DINNER 1536
#define DSTATE 32
#define NHEADS 24
#define HEADDIM 64
#define CONVDIM 1600
#define DINPROJ 3160
#define NPAD 3200
#define SEQ 512
#define MROWS 1024   // B*SEQ = 2*512
#define CL 64        // chunk length
#define NCH 8        // chunks per sequence

typedef __attribute__((ext_vector_type(8))) short bf16x8;
typedef __attribute__((ext_vector_type(4))) float f32x4;

__device__ __forceinline__ ushort f2bs(float v) {
  __hip_bfloat16 b = __float2bfloat16(v);
  return __builtin_bit_cast(unsigned short, b);
}
__device__ __forceinline__ float b2f(ushort u) {
  return __uint_as_float(((uint)u) << 16);
}

__device__ __forceinline__ void gld16(const void* g, const void* l) {
  __builtin_amdgcn_global_load_lds((const __attribute__((address_space(1))) void*)g,
                                   (__attribute__((address_space(3))) void*)l, 16, 0, 0);
}

__device__ __forceinline__ void wait_vm(int n) {
  switch (n) {
    case 0: asm volatile("s_waitcnt vmcnt(0)" ::: "memory"); break;
    case 2: asm volatile("s_waitcnt vmcnt(2)" ::: "memory"); break;
    case 3: asm volatile("s_waitcnt vmcnt(3)" ::: "memory"); break;
    case 4: asm volatile("s_waitcnt vmcnt(4)" ::: "memory"); break;
    case 6: asm volatile("s_waitcnt vmcnt(6)" ::: "memory"); break;
    default: asm volatile("s_waitcnt vmcnt(8)" ::: "memory"); break;
  }
}

__device__ __forceinline__ float block_reduce_sum(float v, float* ws4) {
#pragma unroll
  for (int o = 32; o > 0; o >>= 1) v += __shfl_xor(v, o, 64);
  int wid = threadIdx.x >> 6;
  if ((threadIdx.x & 63) == 0) ws4[wid] = v;
  __syncthreads();
  return ws4[0] + ws4[1] + ws4[2] + ws4[3];
}

// ---------------- prep: input RMSNorm (blocks 0..1023) + all weight f2b (rest) ----------
__global__ __launch_bounds__(256) void prep_kernel(
    const float* __restrict__ x, const float* __restrict__ w, ushort* __restrict__ h,
    const float* __restrict__ s0, const float* __restrict__ s1,
    const float* __restrict__ s2, const float* __restrict__ s3,
    const float* __restrict__ s4, ushort* __restrict__ d) {
  if (blockIdx.x < MROWS) {
    __shared__ float ws4[4];
    int m = blockIdx.x;
    const float* xr = x + (size_t)m * DMODEL;
    float v[3];
    float ss = 0.f;
#pragma unroll
    for (int i = 0; i < 3; ++i) {
      v[i] = xr[threadIdx.x + i * 256];
      ss += v[i] * v[i];
    }
    ss = block_reduce_sum(ss, ws4);
    float sc = rsqrtf(ss / (float)DMODEL + 1e-5f);
    ushort* hr = h + (size_t)m * DMODEL;
#pragma unroll
    for (int i = 0; i < 3; ++i) {
      int c = threadIdx.x + i * 256;
      hr[c] = f2bs(v[i] * sc * w[c]);
    }
    return;
  }
  constexpr size_t NP_IN = (size_t)NPAD * DMODEL;
  constexpr size_t NE_IN = (size_t)DINPROJ * DMODEL;
  constexpr size_t NE_O = (size_t)DMODEL * DINNER;
  size_t i = (((size_t)blockIdx.x - MROWS) * 256 + threadIdx.x) * 4;
  const float* src;
  size_t off, ne;
  if (i < NP_IN) { src = s0; off = i; ne = NE_IN; }
  else if (i < 2 * NP_IN) { src = s1; off = i - NP_IN; ne = NE_IN; }
  else if (i < 2 * NP_IN + NE_O) { src = s2; off = i - 2 * NP_IN; ne = NE_O; }
  else if (i < 2 * NP_IN + 2 * NE_O) { src = s3; off = i - 2 * NP_IN - NE_O; ne = NE_O; }
  else if (i < 2 * NP_IN + 3 * NE_O) { src = s4; off = i - 2 * NP_IN - 2 * NE_O; ne = NE_O; }
  else return;
  ushort* dp = d + i;
  if (off + 3 < ne) {
    float4 v = *(const float4*)(src + off);
    dp[0] = f2bs(v.x); dp[1] = f2bs(v.y); dp[2] = f2bs(v.z); dp[3] = f2bs(v.w);
  } else {
#pragma unroll
    for (int j = 0; j < 4; ++j) dp[j] = (off + j < ne) ? f2bs(src[off + j]) : (ushort)0;
  }
}

// ---------------- depth-3 pipelined bf16 MFMA GEMM (counted vmcnt, raw barriers) ---------
template <int BM, int BN, bool ADD_X, bool OUT_BF16>
__global__ __launch_bounds__(256) void gemm5(
    const ushort* __restrict__ A, int lda, size_t aZ,
    const ushort* __restrict__ Bw, int ldb, size_t bZ,
    void* __restrict__ Cout, int ldc, size_t cZ,
    const float* __restrict__ X, int ldx, int K) {
  constexpr int AG = BM / 16;       // 1KB stage groups
  constexpr int BG = BN / 16;
  constexpr int LPT = (AG + BG) / 4;  // gld16 per thread per stage
  constexpr int MR = BM / 32;
  constexpr int NR = BN / 32;
  __shared__ ushort As[3][BM * 32];
  __shared__ ushort Bs[3][BN * 32];
  const int t = threadIdx.x, w = t >> 6, l = t & 63;
  int bx, by;
  {
    int gx = gridDim.x, gy = gridDim.y;
    int nwg = gx * gy;
    int flat = blockIdx.y * gx + blockIdx.x;
    int s = (flat & 7) * (nwg >> 3) + (flat >> 3);
    bx = s / gy; by = s % gy;
  }
  const int m0 = by * BM, n0 = bx * BN;
  const int wr = w >> 1, wc = w & 1;
  const int fr = l & 15, fq = l >> 4;
  const int sr = l >> 2, sc2 = (l & 3) * 8;
  const ushort* Ap = A + (size_t)blockIdx.z * aZ;
  const ushort* Bp = Bw + (size_t)blockIdx.z * bZ;

  auto stage = [&](int bb, int k0) {
#pragma unroll
    for (int g = w; g < AG + BG; g += 4) {
      if (g < AG)
        gld16(Ap + (size_t)(m0 + g * 16 + sr) * lda + k0 + sc2, (const char*)&As[bb][0] + g * 1024);
      else
        gld16(Bp + (size_t)(n0 + (g - AG) * 16 + sr) * ldb + k0 + sc2,
              (const char*)&Bs[bb][0] + (g - AG) * 1024);
    }
  };

  f32x4 acc[MR][NR];
#pragma unroll
  for (int m = 0; m < MR; ++m)
#pragma unroll
    for (int n = 0; n < NR; ++n) acc[m][n] = (f32x4){0.f, 0.f, 0.f, 0.f};

  const int nk = K / 32;  // always >= 3 here
  stage(0, 0);
  stage(1, 32);
  stage(2, 64);
  int b = 0;
  for (int k = 0; k < nk; ++k) {
    int rem = nk - 1 - k;
    wait_vm(LPT * (rem < 2 ? rem : 2));   // stage k landed (up to 2 newer in flight)
    __builtin_amdgcn_sched_barrier(0);
    __builtin_amdgcn_s_barrier();         // all waves' stage-k writes visible
    __builtin_amdgcn_sched_barrier(0);
    bf16x8 af[MR], bfr[NR];
#pragma unroll
    for (int m = 0; m < MR; ++m)
      af[m] = *(const bf16x8*)&As[b][(wr * (BM / 2) + m * 16 + fr) * 32 + fq * 8];
#pragma unroll
    for (int n = 0; n < NR; ++n)
      bfr[n] = *(const bf16x8*)&Bs[b][(wc * (BN / 2) + n * 16 + fr) * 32 + fq * 8];
#pragma unroll
    for (int m = 0; m < MR; ++m)
#pragma unroll
      for (int n = 0; n < NR; ++n)
        acc[m][n] = __builtin_amdgcn_mfma_f32_16x16x32_bf16(af[m], bfr[n], acc[m][n], 0, 0, 0);
    __builtin_amdgcn_sched_barrier(0);
    __builtin_amdgcn_s_barrier();         // all waves done reading buf b
    if (k + 3 < nk) stage(b, (k + 3) * 32);
    b = (b == 2) ? 0 : b + 1;
  }

#pragma unroll
  for (int m = 0; m < MR; ++m) {
#pragma unroll
    for (int n = 0; n < NR; ++n) {
      int col = n0 + wc * (BN / 2) + n * 16 + fr;
#pragma unroll
      for (int j = 0; j < 4; ++j) {
        int row = m0 + wr * (BM / 2) + m * 16 + fq * 4 + j;
        float v = acc[m][n][j];
        if (ADD_X) v += X[(size_t)row * ldx + col];
        if (OUT_BF16)
          ((ushort*)Cout + (size_t)blockIdx.z * cZ)[(size_t)row * ldc + col] = f2bs(v);
        else
          ((float*)Cout + (size_t)blockIdx.z * cZ)[(size_t)row * ldc + col] = v;
      }
    }
  }
}

// ---------------- fused scan LDS state ----------------
struct ScanLds {
  ushort raw[68][128];   // 67 rows used: x-head slice [0:64) | B,C [64:128)
  float xs[CL][64];
  float bcs[CL][64];
  float das[CL][2];
};

// stage raw zxb slice, compute dt/a, then conv+silu -> xs/bcs. Ends with __syncthreads.
__device__ __forceinline__ void scan_stage_conv(
    ScanLds& S, const ushort* __restrict__ zxb,
    const float* __restrict__ cw, const float* __restrict__ cb,
    const float* __restrict__ dtb, const float* __restrict__ Al,
    int c, int b, int h, int dir, int t) {
  int r0 = dir ? (SEQ - 1 - c * CL - (CL - 1)) : (c * CL - 3);  // seq row of raw[0]
  const ushort* zb = zxb + (size_t)(b * SEQ) * 6400 + dir * 3200 + DINNER;  // xBC base
#pragma unroll
  for (int i = 0; i < 5; ++i) {
    int slot = i * 256 + t;
    if (slot < 67 * 16) {
      int j = slot >> 4, seg = (slot >> 3) & 1, o = slot & 7;
      int gr = r0 + j;
      uint4 val = (uint4){0u, 0u, 0u, 0u};
      if (gr >= 0 && gr < SEQ)
        val = *(const uint4*)(zb + (size_t)gr * 6400 + (seg ? DINNER : h * HEADDIM) + o * 8);
      *(uint4*)&S.raw[j][seg * 64 + o * 8] = val;
    }
  }
  if (t < CL) {
    int tau = c * CL + t;
    int prow = dir ? (SEQ - 1 - tau) : tau;
    float v = b2f(zxb[(size_t)(b * SEQ + prow) * 6400 + dir * 3200 + DINNER + CONVDIM + h]) + dtb[h];
    float dt = (v > 20.f) ? v : log1pf(expf(v));
    float A = -expf(Al[h]);
    S.das[t][0] = dt;
    S.das[t][1] = expf(dt * A);
  }
  __syncthreads();
#pragma unroll 4
  for (int i = 0; i < 32; ++i) {
    int idx = i * 256 + t;
    int s = idx >> 7, ch = idx & 127;
    int cc = (ch < 64) ? (h * HEADDIM + ch) : (DINNER + ch - 64);
    float acc = cb[cc];
#pragma unroll
    for (int d = 0; d < 4; ++d) {
      if (c * CL + s - d >= 0) {
        int rj = dir ? (63 - s + d) : (s + 3 - d);
        acc = fmaf(b2f(S.raw[rj][ch]), cw[cc * 4 + 3 - d], acc);
      }
    }
    float sv = acc / (1.f + expf(-acc));  // silu
    if (ch < 64) S.xs[s][ch] = sv;
    else S.bcs[s][ch - 64] = sv;
  }
  __syncthreads();
}

// ---------------- scan phase 1 (fused conv): local chunk state + decay ----------------
__global__ __launch_bounds__(256) void scan_p1(
    const ushort* __restrict__ zxb,
    const float* __restrict__ cw0, const float* __restrict__ cb0,
    const float* __restrict__ dtb0, const float* __restrict__ Al0,
    const float* __restrict__ cw1, const float* __restrict__ cb1,
    const float* __restrict__ dtb1, const float* __restrict__ Al1,
    float* __restrict__ sbuf, float* __restrict__ abuf) {
  __shared__ ScanLds S;
  int c = blockIdx.x, bh = blockIdx.y, dir = blockIdx.z;
  int b = bh / NHEADS, h = bh % NHEADS;
  int t = threadIdx.x, p = t >> 2, q = t & 3;
  scan_stage_conv(S, zxb, dir ? cw1 : cw0, dir ? cb1 : cb0, dir ? dtb1 : dtb0,
                  dir ? Al1 : Al0, c, b, h, dir, t);
  float hst[8];
#pragma unroll
  for (int j = 0; j < 8; ++j) hst[j] = 0.f;
  float alpha = 1.f;
#pragma unroll 8
  for (int s = 0; s < CL; ++s) {
    float xp = S.xs[s][p];
    float dt_s = S.das[s][0], a_s = S.das[s][1];
    float cx = dt_s * xp;
    alpha *= a_s;
    float4 B0 = *(const float4*)&S.bcs[s][q * 8];
    float4 B1 = *(const float4*)&S.bcs[s][q * 8 + 4];
    float Bv[8] = {B0.x, B0.y, B0.z, B0.w, B1.x, B1.y, B1.z, B1.w};
#pragma unroll
    for (int j = 0; j < 8; ++j) hst[j] = fmaf(a_s, hst[j], cx * Bv[j]);
  }
  float* sp = sbuf + (((size_t)(dir * 48 + bh)) * NCH + c) * 2048 + p * 32 + q * 8;
  *(float4*)sp = (float4){hst[0], hst[1], hst[2], hst[3]};
  *(float4*)(sp + 4) = (float4){hst[4], hst[5], hst[6], hst[7]};
  if (t == 0) abuf[(dir * 48 + bh) * NCH + c] = alpha;
}

// ---------------- scan phase 3 (fused conv): predecessor combine + recurrence -> y ------
__global__ __launch_bounds__(256) void scan_p3(
    const ushort* __restrict__ zxb,
    const float* __restrict__ cw0, const float* __restrict__ cb0,
    const float* __restrict__ dtb0, const float* __restrict__ Al0,
    const float* __restrict__ cw1, const float* __restrict__ cb1,
    const float* __restrict__ dtb1, const float* __restrict__ Al1,
    const float* __restrict__ sbuf, const float* __restrict__ abuf,
    const float* __restrict__ Dp0, const float* __restrict__ Dp1,
    float* __restrict__ y) {
  __shared__ ScanLds S;
  int c = blockIdx.x, bh = blockIdx.y, dir = blockIdx.z;
  int b = bh / NHEADS, h = bh % NHEADS;
  int t = threadIdx.x, p = t >> 2, q = t & 3;
  scan_stage_conv(S, zxb, dir ? cw1 : cw0, dir ? cb1 : cb0, dir ? dtb1 : dtb0,
                  dir ? Al1 : Al0, c, b, h, dir, t);
  float hst[8];
#pragma unroll
  for (int j = 0; j < 8; ++j) hst[j] = 0.f;
  for (int cc = 0; cc < c; ++cc) {
    const float* sp = sbuf + (((size_t)(dir * 48 + bh)) * NCH + cc) * 2048 + p * 32 + q * 8;
    float4 s0 = *(const float4*)sp;
    float4 s1 = *(const float4*)(sp + 4);
    float al = abuf[(dir * 48 + bh) * NCH + cc];
    float sv[8] = {s0.x, s0.y, s0.z, s0.w, s1.x, s1.y, s1.z, s1.w};
#pragma unroll
    for (int j = 0; j < 8; ++j) hst[j] = fmaf(al, hst[j], sv[j]);
  }
  float Dv = (dir ? Dp1 : Dp0)[h];
#pragma unroll 8
  for (int s = 0; s < CL; ++s) {
    float xp = S.xs[s][p];
    float dt_s = S.das[s][0], a_s = S.das[s][1];
    float cx = dt_s * xp;
    float4 B0 = *(const float4*)&S.bcs[s][q * 8];
    float4 B1 = *(const float4*)&S.bcs[s][q * 8 + 4];
    float4 C0 = *(const float4*)&S.bcs[s][32 + q * 8];
    float4 C1 = *(const float4*)&S.bcs[s][32 + q * 8 + 4];
    float Bv[8] = {B0.x, B0.y, B0.z, B0.w, B1.x, B1.y, B1.z, B1.w};
    float Cv[8] = {C0.x, C0.y, C0.z, C0.w, C1.x, C1.y, C1.z, C1.w};
    float acc = 0.f;
#pragma unroll
    for (int j = 0; j < 8; ++j) {
      hst[j] = fmaf(a_s, hst[j], cx * Bv[j]);
      acc = fmaf(hst[j], Cv[j], acc);
    }
    acc += __shfl_xor(acc, 1, 64);
    acc += __shfl_xor(acc, 2, 64);
    if (q == 0) {
      int tau = c * CL + s;
      int prow = dir ? (SEQ - 1 - tau) : tau;
      y[((size_t)dir * MROWS + b * SEQ + prow) * DINNER + h * HEADDIM + p] = fmaf(Dv, xp, acc);
    }
  }
}

// ---------------- gated RMSNorm -> yn (bf16) ----------------
__global__ __launch_bounds__(256) void gated_norm_kernel(
    const float* __restrict__ y,
    const ushort* __restrict__ zxb,
    const float* __restrict__ nw0, const float* __restrict__ nw1,
    ushort* __restrict__ yn) {
  __shared__ float ws4[4];
  int m = blockIdx.x;
  int dir = blockIdx.y;
  const float* nw = dir ? nw1 : nw0;
  float g[6];
  float ss = 0.f;
#pragma unroll
  for (int i = 0; i < 6; ++i) {
    int c = threadIdx.x + i * 256;
    float yv = y[((size_t)dir * MROWS + m) * DINNER + c];
    float zv = b2f(zxb[(size_t)m * 6400 + dir * 3200 + c]);
    float gg = yv * (zv / (1.f + expf(-zv)));
    g[i] = gg;
    ss += gg * gg;
  }
  ss = block_reduce_sum(ss, ws4);
  float sc = rsqrtf(ss / (float)DINNER + 1e-5f);
#pragma unroll
  for (int i = 0; i < 6; ++i) {
    int c = threadIdx.x + i * 256;
    yn[((size_t)dir * MROWS + m) * DINNER + c] = f2bs(g[i] * sc * nw[c]);
  }
}

// ---------------- launch ----------------
extern "C" void kernel_launch(void* const* d_in, const int* in_sizes, int n_in,
                              void* d_out, int out_size, void* d_ws, size_t ws_size,
                              hipStream_t stream) {
  const float* x = (const float*)d_in[0];
  const float* norm_w = (const float*)d_in[1];
  const float* in_w[2] = {(const float*)d_in[2], (const float*)d_in[10]};
  const float* conv_w[2] = {(const float*)d_in[3], (const float*)d_in[11]};
  const float* conv_b[2] = {(const float*)d_in[4], (const float*)d_in[12]};
  const float* dt_bias[2] = {(const float*)d_in[5], (const float*)d_in[13]};
  const float* A_log[2] = {(const float*)d_in[6], (const float*)d_in[14]};
  const float* Dp[2] = {(const float*)d_in[7], (const float*)d_in[15]};
  const float* nw[2] = {(const float*)d_in[8], (const float*)d_in[16]};
  const float* out_w[2] = {(const float*)d_in[9], (const float*)d_in[17]};
  const float* proj_w = (const float*)d_in[18];
  float* out = (float*)d_out;

  char* p = (char*)d_ws;
  ushort* zxb = (ushort*)p; p += (size_t)MROWS * 6400 * 2;
  float* y = (float*)p;     p += (size_t)2 * MROWS * DINNER * 4;
  float* sbuf = (float*)p;  p += (size_t)96 * NCH * 2048 * 4;
  float* abuf = (float*)p;  p += (size_t)96 * NCH * 4;
  ushort* h = (ushort*)p;   p += (size_t)MROWS * DMODEL * 2;
  ushort* yn = (ushort*)p;  p += (size_t)2 * MROWS * DINNER * 2;
  ushort* cat = (ushort*)p; p += (size_t)MROWS * DINNER * 2;
  ushort* wi = (ushort*)p;  p += (size_t)2 * NPAD * DMODEL * 2;   // contiguous: wi|wo|wp
  ushort* wo = (ushort*)p;  p += (size_t)2 * DMODEL * DINNER * 2;
  ushort* wp = (ushort*)p;  p += (size_t)DMODEL * DINNER * 2;

  // prep: rmsnorm (1024 blocks) + weight f2b, one dispatch
  {
    size_t tot = 2 * (size_t)NPAD * DMODEL + 3 * (size_t)DMODEL * DINNER;
    int fblocks = (int)((tot / 4 + 255) / 256);
    prep_kernel<<<MROWS + fblocks, 256, 0, stream>>>(x, norm_w, h, in_w[0], in_w[1],
                                                     out_w[0], out_w[1], proj_w, wi);
  }

  // in_proj both dirs: zxb[1024][6400] = h @ [wi0|wi1]^T (bf16 out), 128x128 tiles, 400 blocks
  {
    dim3 g(6400 / 128, MROWS / 128, 1);
    gemm5<128, 128, false, true><<<g, 256, 0, stream>>>(h, DMODEL, 0, wi, DMODEL, 0,
                                                        zxb, 6400, 0, nullptr, 0, DMODEL);
  }

  // fused conv+scan (phase1: local states; phase3: combine + recurrence -> y)
  scan_p1<<<dim3(NCH, 48, 2), 256, 0, stream>>>(
      zxb, conv_w[0], conv_b[0], dt_bias[0], A_log[0],
      conv_w[1], conv_b[1], dt_bias[1], A_log[1], sbuf, abuf);
  scan_p3<<<dim3(NCH, 48, 2), 256, 0, stream>>>(
      zxb, conv_w[0], conv_b[0], dt_bias[0], A_log[0],
      conv_w[1], conv_b[1], dt_bias[1], A_log[1], sbuf, abuf, Dp[0], Dp[1], y);

  gated_norm_kernel<<<dim3(MROWS, 2), 256, 0, stream>>>(y, zxb, nw[0], nw[1], yn);

  // out_proj both dirs: cat[:, dir*768 +: 768] = yn[dir] @ wo[dir]^T  (64x64, 384 blocks)
  {
    dim3 g(DMODEL / 64, MROWS / 64, 2);
    gemm5<64, 64, false, true><<<g, 256, 0, stream>>>(
        yn, DINNER, (size_t)MROWS * DINNER, wo, DINNER, (size_t)DMODEL * DINNER,
        cat, DINNER, (size_t)DMODEL, nullptr, 0, DINNER);
  }

  // final: out = x + cat @ wp^T  (64x64, 192 blocks)
  {
    dim3 g(DMODEL / 64, MROWS / 64, 1);
    gemm5<64, 64, true, false><<<g, 256, 0, stream>>>(cat, DINNER, 0, wp, DINNER, 0,
                                                      out, DMODEL, 0, x, DMODEL, DINNER);
  }
}

// Round 10
// 123.938 us; speedup vs baseline: 1.2411x; 1.2411x over previous
//
#include <hip/hip_runtime.h>
#include <hip/hip_bf16.h>

#define DMODEL 768
#define DINNER 1536
#define DSTATE 32
#define NHEADS 24
#define HEADDIM 64
#define CONVDIM 1600
#define DINPROJ 3160
#define NPAD 3200
#define SEQ 512
#define MROWS 1024   // B*SEQ = 2*512
#define CL 64        // chunk length
#define NCH 8        // chunks per sequence

typedef __attribute__((ext_vector_type(8))) short bf16x8;
typedef __attribute__((ext_vector_type(4))) float f32x4;

__device__ __forceinline__ ushort f2bs(float v) {
  __hip_bfloat16 b = __float2bfloat16(v);
  return __builtin_bit_cast(unsigned short, b);
}
__device__ __forceinline__ float b2f(ushort u) {
  return __uint_as_float(((uint)u) << 16);
}
__device__ __forceinline__ float b2f_lo(uint u) { return __uint_as_float(u << 16); }
__device__ __forceinline__ float b2f_hi(uint u) { return __uint_as_float(u & 0xffff0000u); }

__device__ __forceinline__ void gld16(const void* g, const void* l) {
  __builtin_amdgcn_global_load_lds((const __attribute__((address_space(1))) void*)g,
                                   (__attribute__((address_space(3))) void*)l, 16, 0, 0);
}

__device__ __forceinline__ void wait_vm(int n) {
  switch (n) {
    case 0: asm volatile("s_waitcnt vmcnt(0)" ::: "memory"); break;
    case 2: asm volatile("s_waitcnt vmcnt(2)" ::: "memory"); break;
    case 3: asm volatile("s_waitcnt vmcnt(3)" ::: "memory"); break;
    case 4: asm volatile("s_waitcnt vmcnt(4)" ::: "memory"); break;
    case 6: asm volatile("s_waitcnt vmcnt(6)" ::: "memory"); break;
    default: asm volatile("s_waitcnt vmcnt(8)" ::: "memory"); break;
  }
}

__device__ __forceinline__ float block_reduce_sum(float v, float* ws4) {
#pragma unroll
  for (int o = 32; o > 0; o >>= 1) v += __shfl_xor(v, o, 64);
  int wid = threadIdx.x >> 6;
  if ((threadIdx.x & 63) == 0) ws4[wid] = v;
  __syncthreads();
  return ws4[0] + ws4[1] + ws4[2] + ws4[3];
}

// ---------------- prep: input RMSNorm (blocks 0..1023) + all weight f2b (rest) ----------
__global__ __launch_bounds__(256) void prep_kernel(
    const float* __restrict__ x, const float* __restrict__ w, ushort* __restrict__ h,
    const float* __restrict__ s0, const float* __restrict__ s1,
    const float* __restrict__ s2, const float* __restrict__ s3,
    const float* __restrict__ s4, ushort* __restrict__ d) {
  if (blockIdx.x < MROWS) {
    __shared__ float ws4[4];
    int m = blockIdx.x;
    const float* xr = x + (size_t)m * DMODEL;
    float v[3];
    float ss = 0.f;
#pragma unroll
    for (int i = 0; i < 3; ++i) {
      v[i] = xr[threadIdx.x + i * 256];
      ss += v[i] * v[i];
    }
    ss = block_reduce_sum(ss, ws4);
    float sc = rsqrtf(ss / (float)DMODEL + 1e-5f);
    ushort* hr = h + (size_t)m * DMODEL;
#pragma unroll
    for (int i = 0; i < 3; ++i) {
      int c = threadIdx.x + i * 256;
      hr[c] = f2bs(v[i] * sc * w[c]);
    }
    return;
  }
  constexpr size_t NP_IN = (size_t)NPAD * DMODEL;
  constexpr size_t NE_IN = (size_t)DINPROJ * DMODEL;
  constexpr size_t NE_O = (size_t)DMODEL * DINNER;
  size_t i = (((size_t)blockIdx.x - MROWS) * 256 + threadIdx.x) * 4;
  const float* src;
  size_t off, ne;
  if (i < NP_IN) { src = s0; off = i; ne = NE_IN; }
  else if (i < 2 * NP_IN) { src = s1; off = i - NP_IN; ne = NE_IN; }
  else if (i < 2 * NP_IN + NE_O) { src = s2; off = i - 2 * NP_IN; ne = NE_O; }
  else if (i < 2 * NP_IN + 2 * NE_O) { src = s3; off = i - 2 * NP_IN - NE_O; ne = NE_O; }
  else if (i < 2 * NP_IN + 3 * NE_O) { src = s4; off = i - 2 * NP_IN - 2 * NE_O; ne = NE_O; }
  else return;
  ushort* dp = d + i;
  if (off + 3 < ne) {
    float4 v = *(const float4*)(src + off);
    dp[0] = f2bs(v.x); dp[1] = f2bs(v.y); dp[2] = f2bs(v.z); dp[3] = f2bs(v.w);
  } else {
#pragma unroll
    for (int j = 0; j < 4; ++j) dp[j] = (off + j < ne) ? f2bs(src[off + j]) : (ushort)0;
  }
}

// ---------------- depth-3 pipelined bf16 MFMA GEMM (counted vmcnt, raw barriers) ---------
template <int BM, int BN, bool ADD_X, bool OUT_BF16>
__global__ __launch_bounds__(256) void gemm5(
    const ushort* __restrict__ A, int lda, size_t aZ,
    const ushort* __restrict__ Bw, int ldb, size_t bZ,
    void* __restrict__ Cout, int ldc, size_t cZ,
    const float* __restrict__ X, int ldx, int K) {
  constexpr int AG = BM / 16;       // 1KB stage groups
  constexpr int BG = BN / 16;
  constexpr int LPT = (AG + BG) / 4;  // gld16 per thread per stage
  constexpr int MR = BM / 32;
  constexpr int NR = BN / 32;
  __shared__ ushort As[3][BM * 32];
  __shared__ ushort Bs[3][BN * 32];
  const int t = threadIdx.x, w = t >> 6, l = t & 63;
  int bx, by;
  {
    int gx = gridDim.x, gy = gridDim.y;
    int nwg = gx * gy;
    int flat = blockIdx.y * gx + blockIdx.x;
    int s = (flat & 7) * (nwg >> 3) + (flat >> 3);
    bx = s / gy; by = s % gy;
  }
  const int m0 = by * BM, n0 = bx * BN;
  const int wr = w >> 1, wc = w & 1;
  const int fr = l & 15, fq = l >> 4;
  const int sr = l >> 2, sc2 = (l & 3) * 8;
  const ushort* Ap = A + (size_t)blockIdx.z * aZ;
  const ushort* Bp = Bw + (size_t)blockIdx.z * bZ;

  auto stage = [&](int bb, int k0) {
#pragma unroll
    for (int g = w; g < AG + BG; g += 4) {
      if (g < AG)
        gld16(Ap + (size_t)(m0 + g * 16 + sr) * lda + k0 + sc2, (const char*)&As[bb][0] + g * 1024);
      else
        gld16(Bp + (size_t)(n0 + (g - AG) * 16 + sr) * ldb + k0 + sc2,
              (const char*)&Bs[bb][0] + (g - AG) * 1024);
    }
  };

  f32x4 acc[MR][NR];
#pragma unroll
  for (int m = 0; m < MR; ++m)
#pragma unroll
    for (int n = 0; n < NR; ++n) acc[m][n] = (f32x4){0.f, 0.f, 0.f, 0.f};

  const int nk = K / 32;  // always >= 3 here
  stage(0, 0);
  stage(1, 32);
  stage(2, 64);
  int b = 0;
  for (int k = 0; k < nk; ++k) {
    int rem = nk - 1 - k;
    wait_vm(LPT * (rem < 2 ? rem : 2));   // stage k landed (up to 2 newer in flight)
    __builtin_amdgcn_sched_barrier(0);
    __builtin_amdgcn_s_barrier();         // all waves' stage-k writes visible
    __builtin_amdgcn_sched_barrier(0);
    bf16x8 af[MR], bfr[NR];
#pragma unroll
    for (int m = 0; m < MR; ++m)
      af[m] = *(const bf16x8*)&As[b][(wr * (BM / 2) + m * 16 + fr) * 32 + fq * 8];
#pragma unroll
    for (int n = 0; n < NR; ++n)
      bfr[n] = *(const bf16x8*)&Bs[b][(wc * (BN / 2) + n * 16 + fr) * 32 + fq * 8];
#pragma unroll
    for (int m = 0; m < MR; ++m)
#pragma unroll
      for (int n = 0; n < NR; ++n)
        acc[m][n] = __builtin_amdgcn_mfma_f32_16x16x32_bf16(af[m], bfr[n], acc[m][n], 0, 0, 0);
    __builtin_amdgcn_sched_barrier(0);
    __builtin_amdgcn_s_barrier();         // all waves done reading buf b
    if (k + 3 < nk) stage(b, (k + 3) * 32);
    b = (b == 2) ? 0 : b + 1;
  }

#pragma unroll
  for (int m = 0; m < MR; ++m) {
#pragma unroll
    for (int n = 0; n < NR; ++n) {
      int col = n0 + wc * (BN / 2) + n * 16 + fr;
#pragma unroll
      for (int j = 0; j < 4; ++j) {
        int row = m0 + wr * (BM / 2) + m * 16 + fq * 4 + j;
        float v = acc[m][n][j];
        if (ADD_X) v += X[(size_t)row * ldx + col];
        if (OUT_BF16)
          ((ushort*)Cout + (size_t)blockIdx.z * cZ)[(size_t)row * ldc + col] = f2bs(v);
        else
          ((float*)Cout + (size_t)blockIdx.z * cZ)[(size_t)row * ldc + col] = v;
      }
    }
  }
}

// ---------------- causal/anti-causal depthwise conv + silu + dt (bf16 in/out) -----------
__global__ __launch_bounds__(256) void conv_dt_kernel(
    const ushort* __restrict__ zxb,
    const float* __restrict__ cw0, const float* __restrict__ cb0,
    const float* __restrict__ dtb0, const float* __restrict__ Al0,
    const float* __restrict__ cw1, const float* __restrict__ cb1,
    const float* __restrict__ dtb1, const float* __restrict__ Al1,
    ushort* __restrict__ xbc, float* __restrict__ dta) {
  int m = blockIdx.x;
  int dir = blockIdx.y;
  int l = m & (SEQ - 1);
  const float* cw = dir ? cw1 : cw0;
  const float* cb = dir ? cb1 : cb0;
  const ushort* zrow = zxb + (size_t)m * 6400 + dir * 3200 + DINNER;
  ushort* xo = xbc + ((size_t)dir * MROWS + m) * CONVDIM;
  for (int c = threadIdx.x; c < CONVDIM; c += 256) {
    float acc = cb[c];
    if (dir == 0) {
#pragma unroll
      for (int d = 0; d < 4; ++d) {
        if (l - d >= 0) acc = fmaf(b2f(zrow[-(ptrdiff_t)d * 6400 + c]), cw[c * 4 + 3 - d], acc);
      }
    } else {
#pragma unroll
      for (int d = 0; d < 4; ++d) {
        if (l + d < SEQ) acc = fmaf(b2f(zrow[(ptrdiff_t)d * 6400 + c]), cw[c * 4 + 3 - d], acc);
      }
    }
    xo[c] = f2bs(acc / (1.f + expf(-acc)));  // silu
  }
  if (threadIdx.x < NHEADS) {
    int hh = threadIdx.x;
    const float* dtb = dir ? dtb1 : dtb0;
    const float* Al = dir ? Al1 : Al0;
    float v = b2f(zxb[(size_t)m * 6400 + dir * 3200 + DINNER + CONVDIM + hh]) + dtb[hh];
    float dt = (v > 20.f) ? v : log1pf(expf(v));
    float A = -expf(Al[hh]);
    dta[((size_t)dir * MROWS + m) * 48 + hh] = dt;
    dta[((size_t)dir * MROWS + m) * 48 + NHEADS + hh] = expf(dt * A);
  }
}

// ---------------- scan staging from bf16 xbc into fp32 LDS ----------------
__device__ __forceinline__ void scan_stage(
    const ushort* __restrict__ xb, int c, int dir, int h, int t,
    float xs[CL][64], float bcs[CL][64]) {
#pragma unroll
  for (int i = 0; i < 4; ++i) {
    int slot = t + i * 256;
    int s = slot >> 4, seg = (slot >> 3) & 1, o8 = slot & 7;
    int tau = c * CL + s;
    int prow = dir ? (SEQ - 1 - tau) : tau;
    const ushort* rp = xb + (size_t)prow * CONVDIM + (seg ? DINNER : h * HEADDIM) + o8 * 8;
    uint4 u = *(const uint4*)rp;
    float* dst = seg ? &bcs[s][o8 * 8] : &xs[s][o8 * 8];
    uint ua[4] = {u.x, u.y, u.z, u.w};
#pragma unroll
    for (int j = 0; j < 4; ++j) {
      dst[j * 2] = b2f_lo(ua[j]);
      dst[j * 2 + 1] = b2f_hi(ua[j]);
    }
  }
}

// ---------------- scan phase 1: per-chunk local end-state and decay ----------------
__global__ __launch_bounds__(256) void scan_phase1(
    const ushort* __restrict__ xbc, const float* __restrict__ dta,
    float* __restrict__ sbuf, float* __restrict__ abuf) {
  __shared__ float xs[CL][64];
  __shared__ float bcs[CL][64];
  __shared__ float das[CL][2];
  int c = blockIdx.x, bh = blockIdx.y, dir = blockIdx.z;
  int b = bh / NHEADS, h = bh % NHEADS;
  int t = threadIdx.x, p = t >> 2, q = t & 3;
  const ushort* xb = xbc + ((size_t)dir * MROWS + b * SEQ) * CONVDIM;
  scan_stage(xb, c, dir, h, t, xs, bcs);
  if (t < 128) {
    int s = t >> 1, wsel = t & 1;
    int tau = c * CL + s;
    int prow = dir ? (SEQ - 1 - tau) : tau;
    das[s][wsel] = dta[((size_t)dir * MROWS + b * SEQ + prow) * 48 + wsel * NHEADS + h];
  }
  __syncthreads();
  float hst[8];
#pragma unroll
  for (int j = 0; j < 8; ++j) hst[j] = 0.f;
  float alpha = 1.f;
#pragma unroll 8
  for (int s = 0; s < CL; ++s) {
    float xp = xs[s][p];
    float dt_s = das[s][0], a_s = das[s][1];
    float cx = dt_s * xp;
    alpha *= a_s;
    float4 B0 = *(const float4*)&bcs[s][q * 8];
    float4 B1 = *(const float4*)&bcs[s][q * 8 + 4];
    float Bv[8] = {B0.x, B0.y, B0.z, B0.w, B1.x, B1.y, B1.z, B1.w};
#pragma unroll
    for (int j = 0; j < 8; ++j) hst[j] = fmaf(a_s, hst[j], cx * Bv[j]);
  }
  float* sp = sbuf + (((size_t)(dir * 48 + bh)) * NCH + c) * 2048 + p * 32 + q * 8;
  *(float4*)sp = (float4){hst[0], hst[1], hst[2], hst[3]};
  *(float4*)(sp + 4) = (float4){hst[4], hst[5], hst[6], hst[7]};
  if (t == 0) abuf[(dir * 48 + bh) * NCH + c] = alpha;
}

// ---------------- scan phase 3b: predecessor combine + recurrence, write y (bf16) ------
__global__ __launch_bounds__(256) void scan_phase3b(
    const ushort* __restrict__ xbc, const float* __restrict__ dta,
    const float* __restrict__ sbuf, const float* __restrict__ abuf,
    const float* __restrict__ Dp0, const float* __restrict__ Dp1,
    ushort* __restrict__ yb) {
  __shared__ float xs[CL][64];
  __shared__ float bcs[CL][64];
  __shared__ float das[CL][2];
  int c = blockIdx.x, bh = blockIdx.y, dir = blockIdx.z;
  int b = bh / NHEADS, h = bh % NHEADS;
  int t = threadIdx.x, p = t >> 2, q = t & 3;
  const ushort* xb = xbc + ((size_t)dir * MROWS + b * SEQ) * CONVDIM;
  scan_stage(xb, c, dir, h, t, xs, bcs);
  if (t < 128) {
    int s = t >> 1, wsel = t & 1;
    int tau = c * CL + s;
    int prow = dir ? (SEQ - 1 - tau) : tau;
    das[s][wsel] = dta[((size_t)dir * MROWS + b * SEQ + prow) * 48 + wsel * NHEADS + h];
  }

  float hst[8];
#pragma unroll
  for (int j = 0; j < 8; ++j) hst[j] = 0.f;
  for (int cc = 0; cc < c; ++cc) {
    const float* sp = sbuf + (((size_t)(dir * 48 + bh)) * NCH + cc) * 2048 + p * 32 + q * 8;
    float4 s0 = *(const float4*)sp;
    float4 s1 = *(const float4*)(sp + 4);
    float al = abuf[(dir * 48 + bh) * NCH + cc];
    float sv[8] = {s0.x, s0.y, s0.z, s0.w, s1.x, s1.y, s1.z, s1.w};
#pragma unroll
    for (int j = 0; j < 8; ++j) hst[j] = fmaf(al, hst[j], sv[j]);
  }

  float Dv = (dir ? Dp1 : Dp0)[h];
  __syncthreads();
#pragma unroll 8
  for (int s = 0; s < CL; ++s) {
    float xp = xs[s][p];
    float dt_s = das[s][0], a_s = das[s][1];
    float cx = dt_s * xp;
    float4 B0 = *(const float4*)&bcs[s][q * 8];
    float4 B1 = *(const float4*)&bcs[s][q * 8 + 4];
    float4 C0 = *(const float4*)&bcs[s][32 + q * 8];
    float4 C1 = *(const float4*)&bcs[s][32 + q * 8 + 4];
    float Bv[8] = {B0.x, B0.y, B0.z, B0.w, B1.x, B1.y, B1.z, B1.w};
    float Cv[8] = {C0.x, C0.y, C0.z, C0.w, C1.x, C1.y, C1.z, C1.w};
    float acc = 0.f;
#pragma unroll
    for (int j = 0; j < 8; ++j) {
      hst[j] = fmaf(a_s, hst[j], cx * Bv[j]);
      acc = fmaf(hst[j], Cv[j], acc);
    }
    acc += __shfl_xor(acc, 1, 64);
    acc += __shfl_xor(acc, 2, 64);
    if (q == 0) {
      int tau = c * CL + s;
      int prow = dir ? (SEQ - 1 - tau) : tau;
      yb[((size_t)dir * MROWS + b * SEQ + prow) * DINNER + h * HEADDIM + p] =
          f2bs(fmaf(Dv, xp, acc));
    }
  }
}

// ---------------- gated RMSNorm -> yn (bf16), vectorized ----------------
__global__ __launch_bounds__(256) void gated_norm_kernel(
    const ushort* __restrict__ yb,
    const ushort* __restrict__ zxb,
    const float* __restrict__ nw0, const float* __restrict__ nw1,
    ushort* __restrict__ yn) {
  __shared__ float ws4[4];
  int m = blockIdx.x;
  int dir = blockIdx.y;
  const float* nw = dir ? nw1 : nw0;
  const uint* yrow = (const uint*)(yb + ((size_t)dir * MROWS + m) * DINNER);
  const uint* zrow = (const uint*)(zxb + (size_t)m * 6400 + dir * 3200);
  float g[6];
  float ss = 0.f;
#pragma unroll
  for (int i = 0; i < 3; ++i) {
    int c2 = threadIdx.x + i * 256;  // pair index, 768 pairs
    uint yu = yrow[c2];
    uint zu = zrow[c2];
    float y0 = b2f_lo(yu), y1 = b2f_hi(yu);
    float z0 = b2f_lo(zu), z1 = b2f_hi(zu);
    float g0 = y0 * (z0 / (1.f + expf(-z0)));
    float g1 = y1 * (z1 / (1.f + expf(-z1)));
    g[i * 2] = g0; g[i * 2 + 1] = g1;
    ss += g0 * g0 + g1 * g1;
  }
  ss = block_reduce_sum(ss, ws4);
  float sc = rsqrtf(ss / (float)DINNER + 1e-5f);
  uint* yrowo = (uint*)(yn + ((size_t)dir * MROWS + m) * DINNER);
#pragma unroll
  for (int i = 0; i < 3; ++i) {
    int c2 = threadIdx.x + i * 256;
    float2 w2 = *(const float2*)(nw + c2 * 2);
    uint lo = (uint)f2bs(g[i * 2] * sc * w2.x);
    uint hi = (uint)f2bs(g[i * 2 + 1] * sc * w2.y);
    yrowo[c2] = lo | (hi << 16);
  }
}

// ---------------- launch ----------------
extern "C" void kernel_launch(void* const* d_in, const int* in_sizes, int n_in,
                              void* d_out, int out_size, void* d_ws, size_t ws_size,
                              hipStream_t stream) {
  const float* x = (const float*)d_in[0];
  const float* norm_w = (const float*)d_in[1];
  const float* in_w[2] = {(const float*)d_in[2], (const float*)d_in[10]};
  const float* conv_w[2] = {(const float*)d_in[3], (const float*)d_in[11]};
  const float* conv_b[2] = {(const float*)d_in[4], (const float*)d_in[12]};
  const float* dt_bias[2] = {(const float*)d_in[5], (const float*)d_in[13]};
  const float* A_log[2] = {(const float*)d_in[6], (const float*)d_in[14]};
  const float* Dp[2] = {(const float*)d_in[7], (const float*)d_in[15]};
  const float* nw[2] = {(const float*)d_in[8], (const float*)d_in[16]};
  const float* out_w[2] = {(const float*)d_in[9], (const float*)d_in[17]};
  const float* proj_w = (const float*)d_in[18];
  float* out = (float*)d_out;

  char* p = (char*)d_ws;
  ushort* zxb = (ushort*)p; p += (size_t)MROWS * 6400 * 2;
  ushort* xbc = (ushort*)p; p += (size_t)2 * MROWS * CONVDIM * 2;
  float* dta = (float*)p;   p += (size_t)2 * MROWS * 48 * 4;
  ushort* yb = (ushort*)p;  p += (size_t)2 * MROWS * DINNER * 2;
  float* sbuf = (float*)p;  p += (size_t)96 * NCH * 2048 * 4;
  float* abuf = (float*)p;  p += (size_t)96 * NCH * 4;
  ushort* h = (ushort*)p;   p += (size_t)MROWS * DMODEL * 2;
  ushort* yn = (ushort*)p;  p += (size_t)2 * MROWS * DINNER * 2;
  ushort* cat = (ushort*)p; p += (size_t)MROWS * DINNER * 2;
  ushort* wi = (ushort*)p;  p += (size_t)2 * NPAD * DMODEL * 2;   // contiguous: wi|wo|wp
  ushort* wo = (ushort*)p;  p += (size_t)2 * DMODEL * DINNER * 2;
  ushort* wp = (ushort*)p;  p += (size_t)DMODEL * DINNER * 2;

  // prep: rmsnorm (1024 blocks) + weight f2b, one dispatch
  {
    size_t tot = 2 * (size_t)NPAD * DMODEL + 3 * (size_t)DMODEL * DINNER;
    int fblocks = (int)((tot / 4 + 255) / 256);
    prep_kernel<<<MROWS + fblocks, 256, 0, stream>>>(x, norm_w, h, in_w[0], in_w[1],
                                                     out_w[0], out_w[1], proj_w, wi);
  }

  // in_proj both dirs: zxb[1024][6400] = h @ [wi0|wi1]^T (bf16 out), 64x128 tiles, 800 blocks
  {
    dim3 g(6400 / 128, MROWS / 64, 1);
    gemm5<64, 128, false, true><<<g, 256, 0, stream>>>(h, DMODEL, 0, wi, DMODEL, 0,
                                                       zxb, 6400, 0, nullptr, 0, DMODEL);
  }

  conv_dt_kernel<<<dim3(MROWS, 2), 256, 0, stream>>>(
      zxb, conv_w[0], conv_b[0], dt_bias[0], A_log[0],
      conv_w[1], conv_b[1], dt_bias[1], A_log[1], xbc, dta);

  scan_phase1<<<dim3(NCH, 48, 2), 256, 0, stream>>>(xbc, dta, sbuf, abuf);
  scan_phase3b<<<dim3(NCH, 48, 2), 256, 0, stream>>>(xbc, dta, sbuf, abuf, Dp[0], Dp[1], yb);

  gated_norm_kernel<<<dim3(MROWS, 2), 256, 0, stream>>>(yb, zxb, nw[0], nw[1], yn);

  // out_proj both dirs: cat[:, dir*768 +: 768] = yn[dir] @ wo[dir]^T  (64x64, 384 blocks)
  {
    dim3 g(DMODEL / 64, MROWS / 64, 2);
    gemm5<64, 64, false, true><<<g, 256, 0, stream>>>(
        yn, DINNER, (size_t)MROWS * DINNER, wo, DINNER, (size_t)DMODEL * DINNER,
        cat, DINNER, (size_t)DMODEL, nullptr, 0, DINNER);
  }

  // final: out = x + cat @ wp^T  (64x64, 192 blocks)
  {
    dim3 g(DMODEL / 64, MROWS / 64, 1);
    gemm5<64, 64, true, false><<<g, 256, 0, stream>>>(cat, DINNER, 0, wp, DINNER, 0,
                                                      out, DMODEL, 0, x, DMODEL, DINNER);
  }
}